// Round 1
// baseline (114.219 us; speedup 1.0000x reference)
//
#include <hip/hip_runtime.h>
#include <math.h>

#define NSAMP 4
#define NB 64
#define LVOL (64*64*64)

// ---- float <-> order-preserving uint (for atomic min/max on floats) ----
__device__ __forceinline__ unsigned f2ord(float f){
  unsigned u = __float_as_uint(f);
  return (u & 0x80000000u) ? ~u : (u | 0x80000000u);
}
__device__ __forceinline__ float ord2f(unsigned u){
  unsigned v = (u & 0x80000000u) ? (u ^ 0x80000000u) : ~u;
  return __uint_as_float(v);
}

__device__ __forceinline__ float bspline3(float x){
  float t = fabsf(x);
  if (t < 1.0f) return 2.0f/3.0f - t*t + 0.5f*t*t*t;
  if (t < 2.0f){ float w = 2.0f - t; return w*w*w*(1.0f/6.0f); }
  return 0.0f;
}

// ---- kernel 0: init workspace (min/max slots + hist + ratio zeros) ----
__global__ void k_init(unsigned* __restrict__ mm, float* __restrict__ zbuf, int nz){
  int i = blockIdx.x * blockDim.x + threadIdx.x;
  if (i < nz) zbuf[i] = 0.0f;
  if (i < NSAMP * 4) mm[i] = (i & 1) ? 0u : 0xFFFFFFFFu; // even slots=min(init MAX), odd=max(init 0)
}

// ---- kernel 1: per-sample min/max of target and source ----
__global__ __launch_bounds__(256) void k_minmax(const float* __restrict__ tgt,
                                                const float* __restrict__ src,
                                                unsigned* __restrict__ mm){
  const int n = blockIdx.x >> 5;      // 32 blocks per sample
  const int chunk = blockIdx.x & 31;  // 8192 elems per block
  const float4* t4 = (const float4*)(tgt + (size_t)n * LVOL) + (size_t)chunk * 2048;
  const float4* s4 = (const float4*)(src + (size_t)n * LVOL) + (size_t)chunk * 2048;
  float tmn = INFINITY, tmx = -INFINITY, smn = INFINITY, smx = -INFINITY;
  for (int i = threadIdx.x; i < 2048; i += 256){
    float4 a = t4[i];
    tmn = fminf(tmn, fminf(fminf(a.x, a.y), fminf(a.z, a.w)));
    tmx = fmaxf(tmx, fmaxf(fmaxf(a.x, a.y), fmaxf(a.z, a.w)));
    float4 b = s4[i];
    smn = fminf(smn, fminf(fminf(b.x, b.y), fminf(b.z, b.w)));
    smx = fmaxf(smx, fmaxf(fmaxf(b.x, b.y), fmaxf(b.z, b.w)));
  }
  for (int off = 32; off; off >>= 1){
    tmn = fminf(tmn, __shfl_down(tmn, off));
    tmx = fmaxf(tmx, __shfl_down(tmx, off));
    smn = fminf(smn, __shfl_down(smn, off));
    smx = fmaxf(smx, __shfl_down(smx, off));
  }
  __shared__ float red[4][4];
  const int wave = threadIdx.x >> 6, lane = threadIdx.x & 63;
  if (lane == 0){ red[wave][0]=tmn; red[wave][1]=tmx; red[wave][2]=smn; red[wave][3]=smx; }
  __syncthreads();
  if (threadIdx.x == 0){
    for (int w = 1; w < 4; ++w){
      tmn = fminf(tmn, red[w][0]); tmx = fmaxf(tmx, red[w][1]);
      smn = fminf(smn, red[w][2]); smx = fmaxf(smx, red[w][3]);
    }
    atomicMin(&mm[n*4+0], f2ord(tmn));
    atomicMax(&mm[n*4+1], f2ord(tmx));
    atomicMin(&mm[n*4+2], f2ord(smn));
    atomicMax(&mm[n*4+3], f2ord(smx));
  }
}

// ---- kernel 2: joint histogram via sparse 4x4 B-spline scatter ----
__device__ __forceinline__ void scatter16(float* sh, float u, float v){
  // u,v in [0,64]; weights nonzero only for bins floor-1..floor+2
  int iu = (int)floorf(u);
  int iv = (int)floorf(v);
  float wu[4], wv[4];
  #pragma unroll
  for (int k = 0; k < 4; ++k){
    wu[k] = bspline3(u - (float)(iu - 1 + k));
    wv[k] = bspline3(v - (float)(iv - 1 + k));
  }
  #pragma unroll
  for (int a = 0; a < 4; ++a){
    int bt = iu - 1 + a;
    if ((unsigned)bt >= (unsigned)NB) continue;
    #pragma unroll
    for (int b = 0; b < 4; ++b){
      int bs = iv - 1 + b;
      if ((unsigned)bs >= (unsigned)NB) continue;
      atomicAdd(&sh[bt * NB + bs], wu[a] * wv[b]);
    }
  }
}

__global__ __launch_bounds__(256) void k_hist(const float* __restrict__ tgt,
                                              const float* __restrict__ src,
                                              const unsigned* __restrict__ mm,
                                              float* __restrict__ hist){
  const int n = blockIdx.x >> 6;      // 64 chunks per sample
  const int chunk = blockIdx.x & 63;  // 4096 elems per block
  __shared__ float sh[NB * NB];
  for (int i = threadIdx.x; i < NB * NB; i += 256) sh[i] = 0.0f;
  const float tmn = ord2f(mm[n*4+0]);
  const float tmx = ord2f(mm[n*4+1]);
  const float smn = ord2f(mm[n*4+2]);
  const float smx = ord2f(mm[n*4+3]);
  const float st = (float)NB / (tmx - tmn + 1e-12f);
  const float ss = (float)NB / (smx - smn + 1e-12f);
  __syncthreads();
  const size_t base = (size_t)n * LVOL + (size_t)chunk * 4096;
  const float4* t4 = (const float4*)(tgt + base);
  const float4* s4 = (const float4*)(src + base);
  for (int i = threadIdx.x; i < 1024; i += 256){
    float4 a = t4[i];
    float4 b = s4[i];
    scatter16(sh, (a.x - tmn) * st, (b.x - smn) * ss);
    scatter16(sh, (a.y - tmn) * st, (b.y - smn) * ss);
    scatter16(sh, (a.z - tmn) * st, (b.z - smn) * ss);
    scatter16(sh, (a.w - tmn) * st, (b.w - smn) * ss);
  }
  __syncthreads();
  float* gh = hist + n * NB * NB;
  for (int i = threadIdx.x; i < NB * NB; i += 256){
    float v = sh[i];
    if (v != 0.0f) atomicAdd(&gh[i], v);
  }
}

// ---- kernel 3: per-sample entropies and NMI ratio ----
__global__ __launch_bounds__(256) void k_entropy(const float* __restrict__ hist,
                                                 float* __restrict__ ratio){
  const int n = blockIdx.x;
  const float* h = hist + n * NB * NB;
  __shared__ float rowsum[NB], colsum[NB];
  __shared__ float wr1[4], wr2[4];
  __shared__ float S_sh;
  if (threadIdx.x < NB){ rowsum[threadIdx.x] = 0.0f; colsum[threadIdx.x] = 0.0f; }
  __syncthreads();
  const int r  = threadIdx.x >> 2;        // each thread: 16 contiguous elems of one row
  const int c0 = (threadIdx.x & 3) * 16;
  float hv[16];
  float rsum = 0.0f;
  #pragma unroll
  for (int k = 0; k < 16; ++k){ hv[k] = h[r * NB + c0 + k]; rsum += hv[k]; }
  atomicAdd(&rowsum[r], rsum);
  #pragma unroll
  for (int k = 0; k < 16; ++k) atomicAdd(&colsum[c0 + k], hv[k]);
  // total sum
  float part = rsum;
  for (int off = 32; off; off >>= 1) part += __shfl_down(part, off);
  if ((threadIdx.x & 63) == 0) wr1[threadIdx.x >> 6] = part;
  __syncthreads();   // also makes rowsum/colsum atomics visible
  if (threadIdx.x == 0) S_sh = wr1[0] + wr1[1] + wr1[2] + wr1[3];
  __syncthreads();
  const float invS = 1.0f / S_sh;
  // joint entropy
  float ej = 0.0f;
  #pragma unroll
  for (int k = 0; k < 16; ++k){
    float p = hv[k] * invS;
    ej -= p * logf(p + 1e-12f);
  }
  for (int off = 32; off; off >>= 1) ej += __shfl_down(ej, off);
  if ((threadIdx.x & 63) == 0) wr2[threadIdx.x >> 6] = ej;
  // marginal entropies (wave 0 only; 64 lanes = 64 bins)
  float em = 0.0f;
  if (threadIdx.x < NB){
    float pt = rowsum[threadIdx.x] * invS;
    float ps = colsum[threadIdx.x] * invS;
    em = -pt * logf(pt + 1e-12f) - ps * logf(ps + 1e-12f);
    for (int off = 32; off; off >>= 1) em += __shfl_down(em, off);
  }
  __syncthreads();
  if (threadIdx.x == 0){
    float EJ = wr2[0] + wr2[1] + wr2[2] + wr2[3];
    ratio[n] = em / EJ;   // (Ht + Hs) / Hj
  }
}

// ---- kernel 4: final -mean over samples ----
__global__ void k_final(const float* __restrict__ ratio, float* __restrict__ out){
  if (threadIdx.x == 0)
    out[0] = -0.25f * (ratio[0] + ratio[1] + ratio[2] + ratio[3]);
}

extern "C" void kernel_launch(void* const* d_in, const int* in_sizes, int n_in,
                              void* d_out, int out_size, void* d_ws, size_t ws_size,
                              hipStream_t stream){
  const float* tgt = (const float*)d_in[0];
  const float* src = (const float*)d_in[1];
  float* out = (float*)d_out;
  // workspace layout: [0..64) uint minmax (16 used) | [256..) hist 4*4096 f32 | ratio 4 f32
  unsigned* mm = (unsigned*)d_ws;
  float* hist  = (float*)((char*)d_ws + 256);
  float* ratio = hist + NSAMP * NB * NB;
  const int nz = NSAMP * NB * NB + NSAMP;   // hist + ratio contiguous
  k_init<<<(nz + 255) / 256, 256, 0, stream>>>(mm, hist, nz);
  k_minmax<<<NSAMP * 32, 256, 0, stream>>>(tgt, src, mm);
  k_hist<<<NSAMP * 64, 256, 0, stream>>>(tgt, src, mm, hist);
  k_entropy<<<NSAMP, 256, 0, stream>>>(hist, ratio);
  k_final<<<1, 64, 0, stream>>>(ratio, out);
}